// Round 2
// baseline (205.151 us; speedup 1.0000x reference)
//
#include <hip/hip_runtime.h>

#define N_NODES 32768
#define N_EDGES 16384
#define DEG 4
#define KPE 8
#define DIM 128
#define EDIM 64

typedef float f32x4 __attribute__((ext_vector_type(4)));
typedef __bf16 bf16x8 __attribute__((ext_vector_type(8)));
typedef __bf16 bf16x2 __attribute__((ext_vector_type(2)));
typedef unsigned short u16x8 __attribute__((ext_vector_type(8)));
typedef unsigned int u32;
typedef unsigned int u32x4 __attribute__((ext_vector_type(4)));
typedef int i32x4 __attribute__((ext_vector_type(4)));

static __device__ __forceinline__ unsigned short f2bf(float f) {
  union { float f; unsigned int u; } v; v.f = f;
  unsigned int r = (v.u + 0x7FFFu + ((v.u >> 16) & 1u)) >> 16;
  return (unsigned short)r;
}
static __device__ __forceinline__ float bflo(unsigned int v) {
  union { unsigned int u; float f; } x; x.u = v << 16; return x.f;
}
static __device__ __forceinline__ float bfhi(unsigned int v) {
  union { unsigned int u; float f; } x; x.u = v & 0xffff0000u; return x.f;
}

#if __has_builtin(__builtin_amdgcn_fdot2_f32_bf16)
static __device__ __forceinline__ float dot2bf(unsigned int a, unsigned int b, float c) {
  return __builtin_amdgcn_fdot2_f32_bf16(
      __builtin_bit_cast(bf16x2, a), __builtin_bit_cast(bf16x2, b), c, false);
}
#else
static __device__ __forceinline__ float dot2bf(unsigned int a, unsigned int b, float c) {
  c = fmaf(bflo(a), bflo(b), c);
  return fmaf(bfhi(a), bfhi(b), c);
}
#endif

// ---------------- weight combine: CW=[0.25*Wq@Wlin; Wk@Wlin; Wv@Wlin] (384x128),
// CWE = Wk@Wedge (128x64), Wob = bf16(Wo).
// Also flattens the 2-level index chain uidx[n][32] = enodes[node_edges[n][d]][k]
// (depends only on graph inputs, so it hides here at zero extra launches; removes
// one full dependent L3 round trip from every attn wave). -----------------------
__global__ __launch_bounds__(256) void wprep_kernel(
    const float* __restrict__ Wq, const float* __restrict__ Wk,
    const float* __restrict__ Wv, const float* __restrict__ Wlin,
    const float* __restrict__ Wedge, const float* __restrict__ Wo,
    const int* __restrict__ node_edges, const int* __restrict__ enodes,
    unsigned short* __restrict__ CW, unsigned short* __restrict__ CWE,
    unsigned short* __restrict__ Wob, int* __restrict__ uidx)
{
  int id = blockIdx.x * 256 + threadIdx.x;
  if (id < 384 * 128) {
    int j = id >> 7, i = id & 127;
    const float* wrow; float scale = 1.0f;
    if (j < 128)      { wrow = Wq + j * 128; scale = 0.25f; }
    else if (j < 256) { wrow = Wk + (j - 128) * 128; }
    else              { wrow = Wv + (j - 256) * 128; }
    float s = 0.f;
    #pragma unroll 8
    for (int m = 0; m < 128; ++m) s += wrow[m] * Wlin[m * 128 + i];
    CW[id] = f2bf(s * scale);
  } else if (id < 384 * 128 + 128 * 64) {
    int id2 = id - 384 * 128; int j = id2 >> 6, t = id2 & 63;
    float s = 0.f;
    #pragma unroll 8
    for (int m = 0; m < 128; ++m) s += Wk[j * 128 + m] * Wedge[m * 64 + t];
    CWE[id2] = f2bf(s);
  } else if (id < 384 * 128 + 128 * 64 + 128 * 128) {
    int id3 = id - (384 * 128 + 128 * 64);
    Wob[id3] = f2bf(Wo[id3]);
  } else {
    // uidx flatten: t = n*DEG + d in [0, 131072); blocks 288..799 land here.
    int t = id - (384 * 128 + 128 * 64 + 128 * 128);
    int e = node_edges[t];
    i32x4 a = *(const i32x4*)(enodes + (size_t)e * KPE);
    i32x4 b = *(const i32x4*)(enodes + (size_t)e * KPE + 4);
    *(i32x4*)(uidx + (size_t)t * KPE)     = a;
    *(i32x4*)(uidx + (size_t)t * KPE + 4) = b;
  }
}

// ---------------- G12: fused g1 + g2 (independent work, one launch) -----------
__global__ __launch_bounds__(256) void g12_kernel(
    const float* __restrict__ x, const unsigned short* __restrict__ CW,
    const float* __restrict__ bq, const float* __restrict__ bv,
    unsigned short* __restrict__ qb, unsigned short* __restrict__ Kb,
    unsigned short* __restrict__ Vb,
    const float* __restrict__ ea, const unsigned short* __restrict__ CWE,
    const float* __restrict__ bk, unsigned short* __restrict__ WeKb)
{
  const int wave = threadIdx.x >> 6, lane = threadIdx.x & 63;
  const int r16 = lane & 15, quad = lane >> 4;

  if (blockIdx.x < 512) {
    const int m0 = blockIdx.x * 64 + wave * 16;
    u16x8 av[4];
    const float* arow = x + (size_t)(m0 + r16) * DIM + quad * 8;
    #pragma unroll
    for (int kk = 0; kk < 4; ++kk) {
      float4 a0 = *(const float4*)(arow + kk * 32);
      float4 a1 = *(const float4*)(arow + kk * 32 + 4);
      u16x8 au;
      au[0] = f2bf(a0.x); au[1] = f2bf(a0.y); au[2] = f2bf(a0.z); au[3] = f2bf(a0.w);
      au[4] = f2bf(a1.x); au[5] = f2bf(a1.y); au[6] = f2bf(a1.z); au[7] = f2bf(a1.w);
      av[kk] = au;
    }
    #pragma unroll
    for (int g = 0; g < 6; ++g) {
      f32x4 acc[4];
      const f32x4 z = {0.f, 0.f, 0.f, 0.f};
      acc[0] = z; acc[1] = z; acc[2] = z; acc[3] = z;
      #pragma unroll
      for (int kk = 0; kk < 4; ++kk) {
        #pragma unroll
        for (int s = 0; s < 4; ++s) {
          u16x8 bu = *(const u16x8*)(CW + (size_t)(g * 64 + s * 16 + r16) * DIM + kk * 32 + quad * 8);
          acc[s] = __builtin_amdgcn_mfma_f32_16x16x32_bf16(
              __builtin_bit_cast(bf16x8, av[kk]), __builtin_bit_cast(bf16x8, bu), acc[s], 0, 0, 0);
        }
      }
      const int arr = g >> 1;               // 0:q 1:K 2:V
      const int colbase = (g & 1) * 64;
      unsigned short* dst = arr == 0 ? qb : (arr == 1 ? Kb : Vb);
      #pragma unroll
      for (int s = 0; s < 4; ++s) {
        int j = colbase + s * 16 + r16;
        float bias = arr == 0 ? 0.25f * bq[j] : (arr == 2 ? bv[j] : 0.f);
        #pragma unroll
        for (int r = 0; r < 4; ++r) {
          int m = m0 + quad * 4 + r;
          dst[(size_t)m * DIM + j] = f2bf(acc[s][r] + bias);
        }
      }
    }
  } else {
    const int idx = blockIdx.x - 512;
    const int m0 = (idx >> 1) * 64 + wave * 16;
    const int n0 = (idx & 1) * 64;
    f32x4 acc[4];
    const f32x4 z = {0.f, 0.f, 0.f, 0.f};
    acc[0] = z; acc[1] = z; acc[2] = z; acc[3] = z;
    const float* arow = ea + (size_t)(m0 + r16) * EDIM + quad * 8;
    #pragma unroll
    for (int kk = 0; kk < 2; ++kk) {
      float4 a0 = *(const float4*)(arow + kk * 32);
      float4 a1 = *(const float4*)(arow + kk * 32 + 4);
      u16x8 au;
      au[0] = f2bf(a0.x); au[1] = f2bf(a0.y); au[2] = f2bf(a0.z); au[3] = f2bf(a0.w);
      au[4] = f2bf(a1.x); au[5] = f2bf(a1.y); au[6] = f2bf(a1.z); au[7] = f2bf(a1.w);
      bf16x8 av = __builtin_bit_cast(bf16x8, au);
      #pragma unroll
      for (int s = 0; s < 4; ++s) {
        u16x8 bu = *(const u16x8*)(CWE + (size_t)(n0 + s * 16 + r16) * EDIM + kk * 32 + quad * 8);
        acc[s] = __builtin_amdgcn_mfma_f32_16x16x32_bf16(
            av, __builtin_bit_cast(bf16x8, bu), acc[s], 0, 0, 0);
      }
    }
    #pragma unroll
    for (int s = 0; s < 4; ++s) {
      int j = n0 + s * 16 + r16;
      float bias = bk[j];
      #pragma unroll
      for (int r = 0; r < 4; ++r) {
        int m = m0 + quad * 4 + r;
        WeKb[(size_t)m * DIM + j] = f2bf(acc[s][r] + bias);
      }
    }
  }
}

// ---------------- G3: per-node attention (1 block = 1 wave = 1 node) ----------
// r6: index chain flattened. uidx[n][32] (precomputed in wprep) + nedges[n] are
// loaded IN PARALLEL (one round trip) instead of the old nedges -> enodes
// dependent chain (two round trips). Issue order, pinned by memory-clobber asm:
//   idx (9 loads, oldest) -> q nt-loads (8) -> [fence] -> K/E DMA (36)
//   -> [fence] -> V loads (32, youngest) -> asm s_waitcnt vmcnt(32)
// vmcnt(32) retires exactly idx+q+DMA (9+8+36=53), leaving the 32 V loads in
// flight under score/softmax compute. q/ctx use nontemporal ops so the stream
// traffic stops thrashing the 4 MB/XCD L2 that the K/V gather tables need.
__global__ __launch_bounds__(64, 4) void attn_kernel(
    const unsigned short* __restrict__ qb, const unsigned short* __restrict__ Kb,
    const unsigned short* __restrict__ Vb, const unsigned short* __restrict__ WeKb,
    const int* __restrict__ nedges, const int* __restrict__ uidx,
    unsigned short* __restrict__ ctxb)
{
  __shared__ __align__(16) unsigned char ldsK[32 * 272];  // K rows, stride 272
  __shared__ __align__(16) unsigned char ldsE[4 * 272];   // WeK rows
  __shared__ __align__(16) float ldsP[8][36];             // P, padded stride
  const int lane = threadIdx.x;
  const int n = blockIdx.x;
  const int l = lane & 31, half = lane >> 5;
  const int h = lane >> 3;                                 // ctx head
  const int c0 = lane * 2;                                 // ctx dim pair

  // --- indices: flattened neighbor rows + edge ids, all independent (1 RT) ---
  const i32x4* up = (const i32x4*)(uidx + (size_t)n * 32);
  i32x4 m0 = __builtin_nontemporal_load(up + 0);
  i32x4 m1 = __builtin_nontemporal_load(up + 1);
  i32x4 m2 = __builtin_nontemporal_load(up + 2);
  i32x4 m3 = __builtin_nontemporal_load(up + 3);
  i32x4 m4 = __builtin_nontemporal_load(up + 4);
  i32x4 m5 = __builtin_nontemporal_load(up + 5);
  i32x4 m6 = __builtin_nontemporal_load(up + 6);
  i32x4 m7 = __builtin_nontemporal_load(up + 7);
  i32x4 e4 = __builtin_nontemporal_load((const i32x4*)(nedges + (size_t)n * DEG));

  // --- q (wave-uniform row): nontemporal, issued before the index wait ---
  const u32x4* qp = (const u32x4*)(qb + (size_t)n * DIM + half * 64);
  u32x4 qv[8];
  #pragma unroll
  for (int ch = 0; ch < 8; ++ch) qv[ch] = __builtin_nontemporal_load(qp + ch);

  // Fence 0: pins idx+q issue before the DMAs (keeps vmcnt math exact).
  asm volatile("" ::: "memory");

  // --- K + WeK rows -> LDS DMA (36 instrs) ---
#define STAGE(ldsdst, table, row) do {                                          \
    const u32* gp_ = (const u32*)((table) + (size_t)(row) * DIM) + lane;        \
    __builtin_amdgcn_global_load_lds(                                           \
        (const __attribute__((address_space(1))) u32*)gp_,                      \
        (__attribute__((address_space(3))) u32*)(ldsdst), 4, 0, 0);             \
  } while (0)
  STAGE(ldsK + 0  * 272, Kb, m0.x); STAGE(ldsK + 1  * 272, Kb, m0.y);
  STAGE(ldsK + 2  * 272, Kb, m0.z); STAGE(ldsK + 3  * 272, Kb, m0.w);
  STAGE(ldsK + 4  * 272, Kb, m1.x); STAGE(ldsK + 5  * 272, Kb, m1.y);
  STAGE(ldsK + 6  * 272, Kb, m1.z); STAGE(ldsK + 7  * 272, Kb, m1.w);
  STAGE(ldsK + 8  * 272, Kb, m2.x); STAGE(ldsK + 9  * 272, Kb, m2.y);
  STAGE(ldsK + 10 * 272, Kb, m2.z); STAGE(ldsK + 11 * 272, Kb, m2.w);
  STAGE(ldsK + 12 * 272, Kb, m3.x); STAGE(ldsK + 13 * 272, Kb, m3.y);
  STAGE(ldsK + 14 * 272, Kb, m3.z); STAGE(ldsK + 15 * 272, Kb, m3.w);
  STAGE(ldsK + 16 * 272, Kb, m4.x); STAGE(ldsK + 17 * 272, Kb, m4.y);
  STAGE(ldsK + 18 * 272, Kb, m4.z); STAGE(ldsK + 19 * 272, Kb, m4.w);
  STAGE(ldsK + 20 * 272, Kb, m5.x); STAGE(ldsK + 21 * 272, Kb, m5.y);
  STAGE(ldsK + 22 * 272, Kb, m5.z); STAGE(ldsK + 23 * 272, Kb, m5.w);
  STAGE(ldsK + 24 * 272, Kb, m6.x); STAGE(ldsK + 25 * 272, Kb, m6.y);
  STAGE(ldsK + 26 * 272, Kb, m6.z); STAGE(ldsK + 27 * 272, Kb, m6.w);
  STAGE(ldsK + 28 * 272, Kb, m7.x); STAGE(ldsK + 29 * 272, Kb, m7.y);
  STAGE(ldsK + 30 * 272, Kb, m7.z); STAGE(ldsK + 31 * 272, Kb, m7.w);
  STAGE(ldsE + 0 * 272, WeKb, e4.x); STAGE(ldsE + 1 * 272, WeKb, e4.y);
  STAGE(ldsE + 2 * 272, WeKb, e4.z); STAGE(ldsE + 3 * 272, WeKb, e4.w);
#undef STAGE

  // Fence 1: pins DMA issue before V issue (makes vmcnt(32) math exact).
  asm volatile("" ::: "memory");

  // --- V rows (coalesced 256 B wave reads) -> regs: youngest 32 VMEM ops ---
  u32 vv[32];
#define VLOAD(t, row) vv[t] = *(const u32*)(Vb + (size_t)(row) * DIM + c0)
  VLOAD(0,  m0.x); VLOAD(1,  m0.y); VLOAD(2,  m0.z); VLOAD(3,  m0.w);
  VLOAD(4,  m1.x); VLOAD(5,  m1.y); VLOAD(6,  m1.z); VLOAD(7,  m1.w);
  VLOAD(8,  m2.x); VLOAD(9,  m2.y); VLOAD(10, m2.z); VLOAD(11, m2.w);
  VLOAD(12, m3.x); VLOAD(13, m3.y); VLOAD(14, m3.z); VLOAD(15, m3.w);
  VLOAD(16, m4.x); VLOAD(17, m4.y); VLOAD(18, m4.z); VLOAD(19, m4.w);
  VLOAD(20, m5.x); VLOAD(21, m5.y); VLOAD(22, m5.z); VLOAD(23, m5.w);
  VLOAD(24, m6.x); VLOAD(25, m6.y); VLOAD(26, m6.z); VLOAD(27, m6.w);
  VLOAD(28, m7.x); VLOAD(29, m7.y); VLOAD(30, m7.z); VLOAD(31, m7.w);
#undef VLOAD

  // Fence 2: retire exactly the oldest 53 ops (idx + q + all DMAs); the 32 V
  // loads remain in flight under the score/softmax compute below.
  asm volatile("s_waitcnt vmcnt(32)" ::: "memory");

  // --- scores: s[hi] = q . (K[l] + WeK[e(l)]) over this half's 64 dims ---
  const unsigned char* krow = ldsK + l * 272 + half * 128;
  const unsigned char* erow = ldsE + (l >> 3) * 272 + half * 128;
  float s[4] = {0.f, 0.f, 0.f, 0.f};
  #pragma unroll
  for (int ch = 0; ch < 8; ++ch) {
    uint4 kc = *(const uint4*)(krow + ch * 16);
    uint4 ec = *(const uint4*)(erow + ch * 16);
    const int hi = ch >> 1;
    float t = s[hi];
    t = dot2bf(qv[ch].x, kc.x, t); t = dot2bf(qv[ch].x, ec.x, t);
    t = dot2bf(qv[ch].y, kc.y, t); t = dot2bf(qv[ch].y, ec.y, t);
    t = dot2bf(qv[ch].z, kc.z, t); t = dot2bf(qv[ch].z, ec.z, t);
    t = dot2bf(qv[ch].w, kc.w, t); t = dot2bf(qv[ch].w, ec.w, t);
    s[hi] = t;
  }

  // --- softmax over the 32 keys (within each 32-lane half-group) ---
  #pragma unroll
  for (int hi = 0; hi < 4; ++hi) {
    float vmax = s[hi];
    #pragma unroll
    for (int off = 16; off >= 1; off >>= 1)
      vmax = fmaxf(vmax, __shfl_xor(vmax, off, 32));
    float ex = __expf(s[hi] - vmax);
    float sum = ex;
    #pragma unroll
    for (int off = 16; off >= 1; off >>= 1)
      sum += __shfl_xor(sum, off, 32);
    ldsP[half * 4 + hi][l] = ex / sum;
  }
  // single-wave block: LDS write->read ordering is just lgkmcnt (compiler).

  // --- ctx: lane = dim pair; V regs (compiler waits precisely), P via LDS ---
  float a0 = 0.f, a1 = 0.f;
  #pragma unroll
  for (int t = 0; t < 8; ++t) {
    float4 p4 = *(const float4*)&ldsP[h][t * 4];
    a0 = fmaf(p4.x, bflo(vv[t * 4 + 0]), a0); a1 = fmaf(p4.x, bfhi(vv[t * 4 + 0]), a1);
    a0 = fmaf(p4.y, bflo(vv[t * 4 + 1]), a0); a1 = fmaf(p4.y, bfhi(vv[t * 4 + 1]), a1);
    a0 = fmaf(p4.z, bflo(vv[t * 4 + 2]), a0); a1 = fmaf(p4.z, bfhi(vv[t * 4 + 2]), a1);
    a0 = fmaf(p4.w, bflo(vv[t * 4 + 3]), a0); a1 = fmaf(p4.w, bfhi(vv[t * 4 + 3]), a1);
  }
  unsigned int pk = (unsigned int)f2bf(a0) | ((unsigned int)f2bf(a1) << 16);
  __builtin_nontemporal_store(pk, (u32*)(ctxb + (size_t)n * DIM + c0));
}

// ---------------- G4: ctx[N,128] @ Wo[128,128]^T + bo, ReLU -> out fp32 -------
__global__ __launch_bounds__(256) void g4_kernel(
    const unsigned short* __restrict__ ctxb, const unsigned short* __restrict__ Wob,
    const float* __restrict__ bo, float* __restrict__ out)
{
  const int wave = threadIdx.x >> 6, lane = threadIdx.x & 63;
  const int r16 = lane & 15, quad = lane >> 4;
  const int m0 = blockIdx.x * 64 + wave * 16;
  const int n0 = blockIdx.y * 64;

  f32x4 acc[4];
  const f32x4 z = {0.f, 0.f, 0.f, 0.f};
  acc[0] = z; acc[1] = z; acc[2] = z; acc[3] = z;

  #pragma unroll
  for (int kk = 0; kk < 4; ++kk) {
    u16x8 au = *(const u16x8*)(ctxb + (size_t)(m0 + r16) * DIM + kk * 32 + quad * 8);
    bf16x8 av = __builtin_bit_cast(bf16x8, au);
    #pragma unroll
    for (int s = 0; s < 4; ++s) {
      u16x8 bu = *(const u16x8*)(Wob + (size_t)(n0 + s * 16 + r16) * DIM + kk * 32 + quad * 8);
      acc[s] = __builtin_amdgcn_mfma_f32_16x16x32_bf16(
          av, __builtin_bit_cast(bf16x8, bu), acc[s], 0, 0, 0);
    }
  }

  #pragma unroll
  for (int s = 0; s < 4; ++s) {
    int j = n0 + s * 16 + r16;
    float bias = bo[j];
    #pragma unroll
    for (int r = 0; r < 4; ++r) {
      int m = m0 + quad * 4 + r;
      float v = acc[s][r] + bias;
      out[(size_t)m * DIM + j] = v > 0.f ? v : 0.f;
    }
  }
}

extern "C" void kernel_launch(void* const* d_in, const int* in_sizes, int n_in,
                              void* d_out, int out_size, void* d_ws, size_t ws_size,
                              hipStream_t stream)
{
  const float* x     = (const float*)d_in[0];
  const float* ea    = (const float*)d_in[1];
  const int* nedges  = (const int*)d_in[2];
  const int* enodes  = (const int*)d_in[3];
  const float* Wlin  = (const float*)d_in[4];
  const float* Wedge = (const float*)d_in[5];
  const float* Wq    = (const float*)d_in[6];
  const float* Wk    = (const float*)d_in[7];
  const float* Wv    = (const float*)d_in[8];
  const float* bq    = (const float*)d_in[9];
  const float* bk    = (const float*)d_in[10];
  const float* bv    = (const float*)d_in[11];
  const float* Wo    = (const float*)d_in[12];
  const float* bo    = (const float*)d_in[13];
  float* out = (float*)d_out;

  unsigned short* wsp = (unsigned short*)d_ws;
  unsigned short* CW   = wsp;  wsp += 384 * 128;
  unsigned short* CWE  = wsp;  wsp += 128 * 64;
  unsigned short* Wob  = wsp;  wsp += 128 * 128;
  unsigned short* qb   = wsp;  wsp += (size_t)N_NODES * DIM;
  unsigned short* Kb   = wsp;  wsp += (size_t)N_NODES * DIM;
  unsigned short* Vb   = wsp;  wsp += (size_t)N_NODES * DIM;
  unsigned short* WeKb = wsp;  wsp += (size_t)N_EDGES * DIM;
  unsigned short* ctxb = wsp;  wsp += (size_t)N_NODES * DIM;
  int* uidx = (int*)wsp;       wsp += (size_t)N_NODES * 32 * 2;  // 32 ints/node

  // grid: 288 blocks of weight-prep work + 512 blocks of uidx flattening
  wprep_kernel<<<dim3(800), dim3(256), 0, stream>>>(
      Wq, Wk, Wv, Wlin, Wedge, Wo, nedges, enodes, CW, CWE, Wob, uidx);
  g12_kernel<<<dim3(1024), dim3(256), 0, stream>>>(x, CW, bq, bv, qb, Kb, Vb, ea, CWE, bk, WeKb);
  attn_kernel<<<dim3(32768), dim3(64), 0, stream>>>(qb, Kb, Vb, WeKb, nedges, uidx, ctxb);
  g4_kernel<<<dim3(512, 2), dim3(256), 0, stream>>>(ctxb, Wob, bo, out);
}

// Round 3
// 204.484 us; speedup vs baseline: 1.0033x; 1.0033x over previous
//
#include <hip/hip_runtime.h>

#define N_NODES 32768
#define N_EDGES 16384
#define DEG 4
#define KPE 8
#define DIM 128
#define EDIM 64

typedef float f32x4 __attribute__((ext_vector_type(4)));
typedef __bf16 bf16x8 __attribute__((ext_vector_type(8)));
typedef __bf16 bf16x2 __attribute__((ext_vector_type(2)));
typedef unsigned short u16x8 __attribute__((ext_vector_type(8)));
typedef unsigned int u32;
typedef unsigned int u32x4 __attribute__((ext_vector_type(4)));
typedef int i32x4 __attribute__((ext_vector_type(4)));

static __device__ __forceinline__ unsigned short f2bf(float f) {
  union { float f; unsigned int u; } v; v.f = f;
  unsigned int r = (v.u + 0x7FFFu + ((v.u >> 16) & 1u)) >> 16;
  return (unsigned short)r;
}
static __device__ __forceinline__ float bflo(unsigned int v) {
  union { unsigned int u; float f; } x; x.u = v << 16; return x.f;
}
static __device__ __forceinline__ float bfhi(unsigned int v) {
  union { unsigned int u; float f; } x; x.u = v & 0xffff0000u; return x.f;
}

#if __has_builtin(__builtin_amdgcn_fdot2_f32_bf16)
static __device__ __forceinline__ float dot2bf(unsigned int a, unsigned int b, float c) {
  return __builtin_amdgcn_fdot2_f32_bf16(
      __builtin_bit_cast(bf16x2, a), __builtin_bit_cast(bf16x2, b), c, false);
}
#else
static __device__ __forceinline__ float dot2bf(unsigned int a, unsigned int b, float c) {
  c = fmaf(bflo(a), bflo(b), c);
  return fmaf(bfhi(a), bfhi(b), c);
}
#endif

// ---------------- weight combine + uidx flatten (unchanged from r6) ----------
__global__ __launch_bounds__(256) void wprep_kernel(
    const float* __restrict__ Wq, const float* __restrict__ Wk,
    const float* __restrict__ Wv, const float* __restrict__ Wlin,
    const float* __restrict__ Wedge, const float* __restrict__ Wo,
    const int* __restrict__ node_edges, const int* __restrict__ enodes,
    unsigned short* __restrict__ CW, unsigned short* __restrict__ CWE,
    unsigned short* __restrict__ Wob, int* __restrict__ uidx)
{
  int id = blockIdx.x * 256 + threadIdx.x;
  if (id < 384 * 128) {
    int j = id >> 7, i = id & 127;
    const float* wrow; float scale = 1.0f;
    if (j < 128)      { wrow = Wq + j * 128; scale = 0.25f; }
    else if (j < 256) { wrow = Wk + (j - 128) * 128; }
    else              { wrow = Wv + (j - 256) * 128; }
    float s = 0.f;
    #pragma unroll 8
    for (int m = 0; m < 128; ++m) s += wrow[m] * Wlin[m * 128 + i];
    CW[id] = f2bf(s * scale);
  } else if (id < 384 * 128 + 128 * 64) {
    int id2 = id - 384 * 128; int j = id2 >> 6, t = id2 & 63;
    float s = 0.f;
    #pragma unroll 8
    for (int m = 0; m < 128; ++m) s += Wk[j * 128 + m] * Wedge[m * 64 + t];
    CWE[id2] = f2bf(s);
  } else if (id < 384 * 128 + 128 * 64 + 128 * 128) {
    int id3 = id - (384 * 128 + 128 * 64);
    Wob[id3] = f2bf(Wo[id3]);
  } else {
    // uidx flatten: t = n*DEG + d in [0, 131072); blocks 288..799 land here.
    int t = id - (384 * 128 + 128 * 64 + 128 * 128);
    int e = node_edges[t];
    i32x4 a = *(const i32x4*)(enodes + (size_t)e * KPE);
    i32x4 b = *(const i32x4*)(enodes + (size_t)e * KPE + 4);
    *(i32x4*)(uidx + (size_t)t * KPE)     = a;
    *(i32x4*)(uidx + (size_t)t * KPE + 4) = b;
  }
}

// ---------------- G12: fused g1 + g2 (unchanged) ------------------------------
__global__ __launch_bounds__(256) void g12_kernel(
    const float* __restrict__ x, const unsigned short* __restrict__ CW,
    const float* __restrict__ bq, const float* __restrict__ bv,
    unsigned short* __restrict__ qb, unsigned short* __restrict__ Kb,
    unsigned short* __restrict__ Vb,
    const float* __restrict__ ea, const unsigned short* __restrict__ CWE,
    const float* __restrict__ bk, unsigned short* __restrict__ WeKb)
{
  const int wave = threadIdx.x >> 6, lane = threadIdx.x & 63;
  const int r16 = lane & 15, quad = lane >> 4;

  if (blockIdx.x < 512) {
    const int m0 = blockIdx.x * 64 + wave * 16;
    u16x8 av[4];
    const float* arow = x + (size_t)(m0 + r16) * DIM + quad * 8;
    #pragma unroll
    for (int kk = 0; kk < 4; ++kk) {
      float4 a0 = *(const float4*)(arow + kk * 32);
      float4 a1 = *(const float4*)(arow + kk * 32 + 4);
      u16x8 au;
      au[0] = f2bf(a0.x); au[1] = f2bf(a0.y); au[2] = f2bf(a0.z); au[3] = f2bf(a0.w);
      au[4] = f2bf(a1.x); au[5] = f2bf(a1.y); au[6] = f2bf(a1.z); au[7] = f2bf(a1.w);
      av[kk] = au;
    }
    #pragma unroll
    for (int g = 0; g < 6; ++g) {
      f32x4 acc[4];
      const f32x4 z = {0.f, 0.f, 0.f, 0.f};
      acc[0] = z; acc[1] = z; acc[2] = z; acc[3] = z;
      #pragma unroll
      for (int kk = 0; kk < 4; ++kk) {
        #pragma unroll
        for (int s = 0; s < 4; ++s) {
          u16x8 bu = *(const u16x8*)(CW + (size_t)(g * 64 + s * 16 + r16) * DIM + kk * 32 + quad * 8);
          acc[s] = __builtin_amdgcn_mfma_f32_16x16x32_bf16(
              __builtin_bit_cast(bf16x8, av[kk]), __builtin_bit_cast(bf16x8, bu), acc[s], 0, 0, 0);
        }
      }
      const int arr = g >> 1;               // 0:q 1:K 2:V
      const int colbase = (g & 1) * 64;
      unsigned short* dst = arr == 0 ? qb : (arr == 1 ? Kb : Vb);
      #pragma unroll
      for (int s = 0; s < 4; ++s) {
        int j = colbase + s * 16 + r16;
        float bias = arr == 0 ? 0.25f * bq[j] : (arr == 2 ? bv[j] : 0.f);
        #pragma unroll
        for (int r = 0; r < 4; ++r) {
          int m = m0 + quad * 4 + r;
          dst[(size_t)m * DIM + j] = f2bf(acc[s][r] + bias);
        }
      }
    }
  } else {
    const int idx = blockIdx.x - 512;
    const int m0 = (idx >> 1) * 64 + wave * 16;
    const int n0 = (idx & 1) * 64;
    f32x4 acc[4];
    const f32x4 z = {0.f, 0.f, 0.f, 0.f};
    acc[0] = z; acc[1] = z; acc[2] = z; acc[3] = z;
    const float* arow = ea + (size_t)(m0 + r16) * EDIM + quad * 8;
    #pragma unroll
    for (int kk = 0; kk < 2; ++kk) {
      float4 a0 = *(const float4*)(arow + kk * 32);
      float4 a1 = *(const float4*)(arow + kk * 32 + 4);
      u16x8 au;
      au[0] = f2bf(a0.x); au[1] = f2bf(a0.y); au[2] = f2bf(a0.z); au[3] = f2bf(a0.w);
      au[4] = f2bf(a1.x); au[5] = f2bf(a1.y); au[6] = f2bf(a1.z); au[7] = f2bf(a1.w);
      bf16x8 av = __builtin_bit_cast(bf16x8, au);
      #pragma unroll
      for (int s = 0; s < 4; ++s) {
        u16x8 bu = *(const u16x8*)(CWE + (size_t)(n0 + s * 16 + r16) * EDIM + kk * 32 + quad * 8);
        acc[s] = __builtin_amdgcn_mfma_f32_16x16x32_bf16(
            av, __builtin_bit_cast(bf16x8, bu), acc[s], 0, 0, 0);
      }
    }
    #pragma unroll
    for (int s = 0; s < 4; ++s) {
      int j = n0 + s * 16 + r16;
      float bias = bk[j];
      #pragma unroll
      for (int r = 0; r < 4; ++r) {
        int m = m0 + quad * 4 + r;
        WeKb[(size_t)m * DIM + j] = f2bf(acc[s][r] + bias);
      }
    }
  }
}

// ---------------- G3: per-node attention, 2-node software pipeline ------------
// r7: 1 wave = 2 nodes (A = 2*bid, B = 2*bid+1), double-buffered LDS.
// Rationale: attn is latency-bound (MfmaUtil 0, VALU 26%, HBM 43%, L2 ~26%);
// concurrency was LDS-capped at ~10 waves/CU (11 KB/block). Doubling work per
// wave gives 7 blocks/CU x 2 streams = 14 gather streams, and node B's
// idx/DMA/V loads fly under node A's score/softmax/ctx compute.
//
// vmcnt ledger (per-wave VMEM issue order; compiler auto-waits cover all
// register reads, the asm waits cover the LDS-DMA -> ds_read dependencies the
// compiler cannot see; memory-clobber asm pins issue order of memory ops):
//   phase A: idxA(9) | DMA_A(36) qA(8) V_A(32) idxB(9)      -> 94 issued
//     wait vmcnt(41) = retire idxA+DMA_A+qA (53)  -> score/softmax A
//     wait vmcnt(0)  = retire V_A + idxB          -> phase B may start
//   phase B: DMA_B(36) qB(8) | ctxA(VALU) | V_B(32) storeA(1) -> 77 issued
//     wait vmcnt(33) = retire DMA_B+qB (44)       -> score/softmax B
//     (compiler waits vv_B before ctx B; storeA may stay in flight)
__global__ __launch_bounds__(64, 2) void attn_kernel(
    const unsigned short* __restrict__ qb, const unsigned short* __restrict__ Kb,
    const unsigned short* __restrict__ Vb, const unsigned short* __restrict__ WeKb,
    const int* __restrict__ nedges, const int* __restrict__ uidx,
    unsigned short* __restrict__ ctxb)
{
  __shared__ __align__(16) unsigned char ldsK[2][32 * 272];  // K rows, stride 272
  __shared__ __align__(16) unsigned char ldsE[2][4 * 272];   // WeK rows
  __shared__ __align__(16) float ldsP[2][8][36];             // P, padded stride
  const int lane = threadIdx.x;
  const int l = lane & 31, half = lane >> 5;
  const int h = lane >> 3;                                 // ctx head
  const int c0 = lane * 2;                                 // ctx dim pair
  const int nA = blockIdx.x * 2, nB = nA + 1;

  // ---- macros --------------------------------------------------------------
#define LOAD_IDX(mv, ev, node) do {                                             \
    const i32x4* up_ = (const i32x4*)(uidx + (size_t)(node) * 32);              \
    mv[0] = __builtin_nontemporal_load(up_ + 0);                                \
    mv[1] = __builtin_nontemporal_load(up_ + 1);                                \
    mv[2] = __builtin_nontemporal_load(up_ + 2);                                \
    mv[3] = __builtin_nontemporal_load(up_ + 3);                                \
    mv[4] = __builtin_nontemporal_load(up_ + 4);                                \
    mv[5] = __builtin_nontemporal_load(up_ + 5);                                \
    mv[6] = __builtin_nontemporal_load(up_ + 6);                                \
    mv[7] = __builtin_nontemporal_load(up_ + 7);                                \
    ev = __builtin_nontemporal_load((const i32x4*)(nedges + (size_t)(node) * DEG)); \
  } while (0)

#define STAGE1(ldsdst, table, row) do {                                         \
    const u32* gp_ = (const u32*)((table) + (size_t)(row) * DIM) + lane;        \
    __builtin_amdgcn_global_load_lds(                                           \
        (const __attribute__((address_space(1))) u32*)gp_,                      \
        (__attribute__((address_space(3))) u32*)(ldsdst), 4, 0, 0);             \
  } while (0)

#define STAGE_ALL(buf, mv, ev) do {                                             \
    STAGE1(ldsK[buf] + 0  * 272, Kb, mv[0].x); STAGE1(ldsK[buf] + 1  * 272, Kb, mv[0].y); \
    STAGE1(ldsK[buf] + 2  * 272, Kb, mv[0].z); STAGE1(ldsK[buf] + 3  * 272, Kb, mv[0].w); \
    STAGE1(ldsK[buf] + 4  * 272, Kb, mv[1].x); STAGE1(ldsK[buf] + 5  * 272, Kb, mv[1].y); \
    STAGE1(ldsK[buf] + 6  * 272, Kb, mv[1].z); STAGE1(ldsK[buf] + 7  * 272, Kb, mv[1].w); \
    STAGE1(ldsK[buf] + 8  * 272, Kb, mv[2].x); STAGE1(ldsK[buf] + 9  * 272, Kb, mv[2].y); \
    STAGE1(ldsK[buf] + 10 * 272, Kb, mv[2].z); STAGE1(ldsK[buf] + 11 * 272, Kb, mv[2].w); \
    STAGE1(ldsK[buf] + 12 * 272, Kb, mv[3].x); STAGE1(ldsK[buf] + 13 * 272, Kb, mv[3].y); \
    STAGE1(ldsK[buf] + 14 * 272, Kb, mv[3].z); STAGE1(ldsK[buf] + 15 * 272, Kb, mv[3].w); \
    STAGE1(ldsK[buf] + 16 * 272, Kb, mv[4].x); STAGE1(ldsK[buf] + 17 * 272, Kb, mv[4].y); \
    STAGE1(ldsK[buf] + 18 * 272, Kb, mv[4].z); STAGE1(ldsK[buf] + 19 * 272, Kb, mv[4].w); \
    STAGE1(ldsK[buf] + 20 * 272, Kb, mv[5].x); STAGE1(ldsK[buf] + 21 * 272, Kb, mv[5].y); \
    STAGE1(ldsK[buf] + 22 * 272, Kb, mv[5].z); STAGE1(ldsK[buf] + 23 * 272, Kb, mv[5].w); \
    STAGE1(ldsK[buf] + 24 * 272, Kb, mv[6].x); STAGE1(ldsK[buf] + 25 * 272, Kb, mv[6].y); \
    STAGE1(ldsK[buf] + 26 * 272, Kb, mv[6].z); STAGE1(ldsK[buf] + 27 * 272, Kb, mv[6].w); \
    STAGE1(ldsK[buf] + 28 * 272, Kb, mv[7].x); STAGE1(ldsK[buf] + 29 * 272, Kb, mv[7].y); \
    STAGE1(ldsK[buf] + 30 * 272, Kb, mv[7].z); STAGE1(ldsK[buf] + 31 * 272, Kb, mv[7].w); \
    STAGE1(ldsE[buf] + 0 * 272, WeKb, ev.x); STAGE1(ldsE[buf] + 1 * 272, WeKb, ev.y); \
    STAGE1(ldsE[buf] + 2 * 272, WeKb, ev.z); STAGE1(ldsE[buf] + 3 * 272, WeKb, ev.w); \
  } while (0)

#define LOAD_Q(qv, node) do {                                                   \
    const u32x4* qp_ = (const u32x4*)(qb + (size_t)(node) * DIM + half * 64);   \
    _Pragma("unroll")                                                           \
    for (int ch = 0; ch < 8; ++ch) qv[ch] = __builtin_nontemporal_load(qp_ + ch); \
  } while (0)

#define VLOAD_ALL(vv, mv) do {                                                  \
    _Pragma("unroll")                                                           \
    for (int t_ = 0; t_ < 8; ++t_) {                                            \
      vv[t_ * 4 + 0] = *(const u32*)(Vb + (size_t)mv[t_].x * DIM + c0);         \
      vv[t_ * 4 + 1] = *(const u32*)(Vb + (size_t)mv[t_].y * DIM + c0);         \
      vv[t_ * 4 + 2] = *(const u32*)(Vb + (size_t)mv[t_].z * DIM + c0);         \
      vv[t_ * 4 + 3] = *(const u32*)(Vb + (size_t)mv[t_].w * DIM + c0);         \
    }                                                                           \
  } while (0)

  // score + softmax into ldsP[buf]
#define SCORE_SM(buf, qv) do {                                                  \
    const unsigned char* krow_ = ldsK[buf] + l * 272 + half * 128;              \
    const unsigned char* erow_ = ldsE[buf] + (l >> 3) * 272 + half * 128;       \
    float s_[4] = {0.f, 0.f, 0.f, 0.f};                                         \
    _Pragma("unroll")                                                           \
    for (int ch = 0; ch < 8; ++ch) {                                            \
      uint4 kc = *(const uint4*)(krow_ + ch * 16);                              \
      uint4 ec = *(const uint4*)(erow_ + ch * 16);                              \
      const int hi = ch >> 1;                                                   \
      float t = s_[hi];                                                         \
      t = dot2bf(qv[ch].x, kc.x, t); t = dot2bf(qv[ch].x, ec.x, t);             \
      t = dot2bf(qv[ch].y, kc.y, t); t = dot2bf(qv[ch].y, ec.y, t);             \
      t = dot2bf(qv[ch].z, kc.z, t); t = dot2bf(qv[ch].z, ec.z, t);             \
      t = dot2bf(qv[ch].w, kc.w, t); t = dot2bf(qv[ch].w, ec.w, t);             \
      s_[hi] = t;                                                               \
    }                                                                           \
    _Pragma("unroll")                                                           \
    for (int hi = 0; hi < 4; ++hi) {                                            \
      float vmax = s_[hi];                                                      \
      _Pragma("unroll")                                                         \
      for (int off = 16; off >= 1; off >>= 1)                                   \
        vmax = fmaxf(vmax, __shfl_xor(vmax, off, 32));                          \
      float ex = __expf(s_[hi] - vmax);                                         \
      float sum = ex;                                                           \
      _Pragma("unroll")                                                         \
      for (int off = 16; off >= 1; off >>= 1)                                   \
        sum += __shfl_xor(sum, off, 32);                                        \
      ldsP[buf][half * 4 + hi][l] = ex / sum;                                   \
    }                                                                           \
  } while (0)

#define CTX_COMPUTE(buf, vv, a0, a1) do {                                       \
    a0 = 0.f; a1 = 0.f;                                                         \
    _Pragma("unroll")                                                           \
    for (int t_ = 0; t_ < 8; ++t_) {                                            \
      float4 p4 = *(const float4*)&ldsP[buf][h][t_ * 4];                        \
      a0 = fmaf(p4.x, bflo(vv[t_ * 4 + 0]), a0); a1 = fmaf(p4.x, bfhi(vv[t_ * 4 + 0]), a1); \
      a0 = fmaf(p4.y, bflo(vv[t_ * 4 + 1]), a0); a1 = fmaf(p4.y, bfhi(vv[t_ * 4 + 1]), a1); \
      a0 = fmaf(p4.z, bflo(vv[t_ * 4 + 2]), a0); a1 = fmaf(p4.z, bfhi(vv[t_ * 4 + 2]), a1); \
      a0 = fmaf(p4.w, bflo(vv[t_ * 4 + 3]), a0); a1 = fmaf(p4.w, bfhi(vv[t_ * 4 + 3]), a1); \
    }                                                                           \
  } while (0)

#define STORE_CTX(node, a0, a1) do {                                            \
    unsigned int pk_ = (unsigned int)f2bf(a0) | ((unsigned int)f2bf(a1) << 16); \
    __builtin_nontemporal_store(pk_, (u32*)(ctxb + (size_t)(node) * DIM + c0)); \
  } while (0)

  // ---- phase A -------------------------------------------------------------
  i32x4 mA[8], eA;
  LOAD_IDX(mA, eA, nA);                       // 9 VMEM (oldest)
  asm volatile("" ::: "memory");
  STAGE_ALL(0, mA, eA);                       // 36 DMA (compiler waits idxA first)
  u32x4 qvA[8];
  LOAD_Q(qvA, nA);                            // 8
  asm volatile("" ::: "memory");
  u32 vvA[32];
  VLOAD_ALL(vvA, mA);                         // 32
  i32x4 mB[8], eB;
  LOAD_IDX(mB, eB, nB);                       // 9  (B idx latency hides under score A)
  asm volatile("" ::: "memory");
  // retire idxA+DMA_A+qA (53 of 94) -> LDS buf0 ready; V_A + idxB stay in flight
  asm volatile("s_waitcnt vmcnt(41)" ::: "memory");

  SCORE_SM(0, qvA);

  asm volatile("" ::: "memory");
  asm volatile("s_waitcnt vmcnt(0)" ::: "memory");   // retire V_A + idxB

  // ---- phase B issue + phase A epilogue ------------------------------------
  STAGE_ALL(1, mB, eB);                       // 36 DMA
  u32x4 qvB[8];
  LOAD_Q(qvB, nB);                            // 8
  asm volatile("" ::: "memory");

  float a0A, a1A;
  CTX_COMPUTE(0, vvA, a0A, a1A);              // VALU+DS, overlaps DMA_B flight
  u32 vvB[32];
  VLOAD_ALL(vvB, mB);                         // 32
  STORE_CTX(nA, a0A, a1A);                    // 1 nt store

  asm volatile("" ::: "memory");
  // retire DMA_B+qB (44 of 77) -> LDS buf1 ready; V_B + storeA stay in flight
  asm volatile("s_waitcnt vmcnt(33)" ::: "memory");

  SCORE_SM(1, qvB);

  float a0B, a1B;
  CTX_COMPUTE(1, vvB, a0B, a1B);              // compiler waits vv_B precisely
  STORE_CTX(nB, a0B, a1B);

#undef LOAD_IDX
#undef STAGE1
#undef STAGE_ALL
#undef LOAD_Q
#undef VLOAD_ALL
#undef SCORE_SM
#undef CTX_COMPUTE
#undef STORE_CTX
}

// ---------------- G4: ctx[N,128] @ Wo[128,128]^T + bo, ReLU -> out fp32 -------
__global__ __launch_bounds__(256) void g4_kernel(
    const unsigned short* __restrict__ ctxb, const unsigned short* __restrict__ Wob,
    const float* __restrict__ bo, float* __restrict__ out)
{
  const int wave = threadIdx.x >> 6, lane = threadIdx.x & 63;
  const int r16 = lane & 15, quad = lane >> 4;
  const int m0 = blockIdx.x * 64 + wave * 16;
  const int n0 = blockIdx.y * 64;

  f32x4 acc[4];
  const f32x4 z = {0.f, 0.f, 0.f, 0.f};
  acc[0] = z; acc[1] = z; acc[2] = z; acc[3] = z;

  #pragma unroll
  for (int kk = 0; kk < 4; ++kk) {
    u16x8 au = *(const u16x8*)(ctxb + (size_t)(m0 + r16) * DIM + kk * 32 + quad * 8);
    bf16x8 av = __builtin_bit_cast(bf16x8, au);
    #pragma unroll
    for (int s = 0; s < 4; ++s) {
      u16x8 bu = *(const u16x8*)(Wob + (size_t)(n0 + s * 16 + r16) * DIM + kk * 32 + quad * 8);
      acc[s] = __builtin_amdgcn_mfma_f32_16x16x32_bf16(
          av, __builtin_bit_cast(bf16x8, bu), acc[s], 0, 0, 0);
    }
  }

  #pragma unroll
  for (int s = 0; s < 4; ++s) {
    int j = n0 + s * 16 + r16;
    float bias = bo[j];
    #pragma unroll
    for (int r = 0; r < 4; ++r) {
      int m = m0 + quad * 4 + r;
      float v = acc[s][r] + bias;
      out[(size_t)m * DIM + j] = v > 0.f ? v : 0.f;
    }
  }
}

extern "C" void kernel_launch(void* const* d_in, const int* in_sizes, int n_in,
                              void* d_out, int out_size, void* d_ws, size_t ws_size,
                              hipStream_t stream)
{
  const float* x     = (const float*)d_in[0];
  const float* ea    = (const float*)d_in[1];
  const int* nedges  = (const int*)d_in[2];
  const int* enodes  = (const int*)d_in[3];
  const float* Wlin  = (const float*)d_in[4];
  const float* Wedge = (const float*)d_in[5];
  const float* Wq    = (const float*)d_in[6];
  const float* Wk    = (const float*)d_in[7];
  const float* Wv    = (const float*)d_in[8];
  const float* bq    = (const float*)d_in[9];
  const float* bk    = (const float*)d_in[10];
  const float* bv    = (const float*)d_in[11];
  const float* Wo    = (const float*)d_in[12];
  const float* bo    = (const float*)d_in[13];
  float* out = (float*)d_out;

  unsigned short* wsp = (unsigned short*)d_ws;
  unsigned short* CW   = wsp;  wsp += 384 * 128;
  unsigned short* CWE  = wsp;  wsp += 128 * 64;
  unsigned short* Wob  = wsp;  wsp += 128 * 128;
  unsigned short* qb   = wsp;  wsp += (size_t)N_NODES * DIM;
  unsigned short* Kb   = wsp;  wsp += (size_t)N_NODES * DIM;
  unsigned short* Vb   = wsp;  wsp += (size_t)N_NODES * DIM;
  unsigned short* WeKb = wsp;  wsp += (size_t)N_EDGES * DIM;
  unsigned short* ctxb = wsp;  wsp += (size_t)N_NODES * DIM;
  int* uidx = (int*)wsp;       wsp += (size_t)N_NODES * 32 * 2;  // 32 ints/node

  wprep_kernel<<<dim3(800), dim3(256), 0, stream>>>(
      Wq, Wk, Wv, Wlin, Wedge, Wo, nedges, enodes, CW, CWE, Wob, uidx);
  g12_kernel<<<dim3(1024), dim3(256), 0, stream>>>(x, CW, bq, bv, qb, Kb, Vb, ea, CWE, bk, WeKb);
  attn_kernel<<<dim3(16384), dim3(64), 0, stream>>>(qb, Kb, Vb, WeKb, nedges, uidx, ctxb);
  g4_kernel<<<dim3(512, 2), dim3(256), 0, stream>>>(ctxb, Wob, bo, out);
}